// Round 4
// baseline (195.373 us; speedup 1.0000x reference)
//
#include <hip/hip_runtime.h>

// LIF recurrence: u_t = decay*u_{t-1} + x_t - o_{t-1}*VTH ; o_t = (u_t - VTH > 0)
// x: [B=64, N=4096, T=100] f32, T contiguous (400 B per neuron row).
//
// R4: barrier-free software pipeline. Single-wave blocks (64 threads) — a wave
// is implicitly synchronized, so NO __syncthreads and therefore no forced
// s_waitcnt vmcnt(0) drain (R2/R3 post-mortem: the barrier drain made each CU
// alternate burst/silence at ~2.3 TB/s regardless of wave count).
// Each block owns 4 slabs (64 neurons x 100 T = 25.6 KB contiguous each) and
// runs a depth-2 pipeline over double-buffered LDS (2 x 25.6 KB):
//   stage(0); stage(1); [consume 0 | stage 2] [consume 1 | stage 3] ...
// so ~25.6 KB stays in flight per wave at all times. 51.2 KB LDS -> 3
// single-wave blocks/CU; 1024 blocks = exactly 4 per CU.
// Stores remain line-perfect (LDS transpose, 1 KB/instr).
//
// Exactness: decay=0.5, o*VTH in {0,0.5} exact; spike compare bit-matches
// the numpy reference (absmax 0.0 in R1-R3).

#define VTH 0.5f
#define T_STEPS 100
#define NSUB 64                       // neurons per slab (DMA granularity: 25 x 1 KB)
#define SUB_FLOATS (NSUB * T_STEPS)   // 6400 floats = 25.6 KB
#define K_INSTR 25                    // 1 KB wave-wide DMA transfers per slab
#define SLABS 4                       // slabs per block

__shared__ float buf0[SUB_FLOATS];
__shared__ float buf1[SUB_FLOATS];

__device__ __forceinline__ void stage_slab(const float* __restrict__ src, float* dst,
                                           int lane) {
    #pragma unroll
    for (int k = 0; k < K_INSTR; ++k) {
        __builtin_amdgcn_global_load_lds(
            (const __attribute__((address_space(1))) float*)(src + k * 256 + lane * 4),
            (__attribute__((address_space(3))) float*)(dst + k * 256),
            16, 0, 0);
    }
}

__device__ __forceinline__ void consume_slab(float* b, float* __restrict__ gout,
                                             int lane, float decay) {
    // compute: lane owns neuron `lane` of this slab; in-place x -> o overwrite
    float4* b4 = (float4*)b;
    float u = 0.0f, o = 0.0f;
    #pragma unroll
    for (int i = 0; i < K_INSTR; ++i) {
        float4 v = b4[lane * K_INSTR + i];
        u = decay * u + v.x - o * VTH; o = (u > VTH) ? 1.0f : 0.0f; v.x = o;
        u = decay * u + v.y - o * VTH; o = (u > VTH) ? 1.0f : 0.0f; v.y = o;
        u = decay * u + v.z - o * VTH; o = (u > VTH) ? 1.0f : 0.0f; v.z = o;
        u = decay * u + v.w - o * VTH; o = (u > VTH) ? 1.0f : 0.0f; v.w = o;
        b4[lane * K_INSTR + i] = v;
    }
    // store: lane-contiguous LDS reads (conflict-free), line-perfect 1 KB stores
    float4* o4 = (float4*)gout;
    #pragma unroll
    for (int k = 0; k < K_INSTR; ++k) {
        o4[k * 64 + lane] = b4[k * 64 + lane];
    }
}

__global__ __launch_bounds__(64) void lif_kernel(const float* __restrict__ x,
                                                 const float* __restrict__ decay_p,
                                                 float* __restrict__ out,
                                                 int n_neurons) {
    const int lane = threadIdx.x;
    const float decay = decay_p[0];
    const size_t base = (size_t)blockIdx.x * (SLABS * SUB_FLOATS);

    const float* __restrict__ xin = x + base;
    float* __restrict__ xout = out + base;

    stage_slab(xin + 0 * SUB_FLOATS, buf0, lane);
    stage_slab(xin + 1 * SUB_FLOATS, buf1, lane);

    // slab 0 from buf0, then prefetch slab 2 into buf0
    consume_slab(buf0, xout + 0 * SUB_FLOATS, lane, decay);
    stage_slab(xin + 2 * SUB_FLOATS, buf0, lane);

    // slab 1 from buf1, then prefetch slab 3 into buf1
    consume_slab(buf1, xout + 1 * SUB_FLOATS, lane, decay);
    stage_slab(xin + 3 * SUB_FLOATS, buf1, lane);

    consume_slab(buf0, xout + 2 * SUB_FLOATS, lane, decay);
    consume_slab(buf1, xout + 3 * SUB_FLOATS, lane, decay);
}

extern "C" void kernel_launch(void* const* d_in, const int* in_sizes, int n_in,
                              void* d_out, int out_size, void* d_ws, size_t ws_size,
                              hipStream_t stream) {
    const float* x = (const float*)d_in[0];
    const float* decay = (const float*)d_in[1];
    float* out = (float*)d_out;

    const int n_neurons = in_sizes[0] / T_STEPS;     // 262,144
    const int grid = n_neurons / (SLABS * NSUB);     // 1024 single-wave blocks

    lif_kernel<<<grid, 64, 0, stream>>>(x, decay, out, n_neurons);
}

// Round 6
// 185.642 us; speedup vs baseline: 1.0524x; 1.0524x over previous
//
#include <hip/hip_runtime.h>

// LIF recurrence: u_t = decay*u_{t-1} + x_t - o_{t-1}*VTH ; o_t = (u_t - VTH > 0)
// x: [B=64, N=4096, T=100] f32, T contiguous (400 B per neuron row).
//
// R6 = R5 with the compile fix: __builtin_nontemporal_store requires a native
// vector type, not HIP's float4 class -> use ext_vector_type(4) float alias.
//
// Structure: same slab/transpose dataflow as R2 (the best round) but staging
// goes through the NORMAL load path (coalesced float4 -> VGPR ->
// ds_write_b128) instead of global_load_lds DMA. R2/R3/R4 all pinned at
// ~2.2-2.4 TB/s across wildly different pipelining structures; the common
// element was the DMA path, so this round A/Bs it directly. Single-wave
// blocks (64 threads, no __syncthreads anywhere), single 25.6 KB LDS buffer
// -> 6 blocks/CU; all 25 loads issued before first LDS write => 25.6 KB in
// flight per wave, ~153 KB/CU. Stores are non-temporal (streamed output).
//
// Exactness: decay=0.5 and o*VTH in {0,0.5} are exact products, so FMA
// contraction cannot perturb u; spike output bit-matches numpy reference
// (absmax 0.0 in R1-R4).

#define VTH 0.5f
#define T_STEPS 100
#define W 64                  // neurons per block == threads per block (1 wave)
#define K 25                  // float4s per neuron row (100 floats)

typedef float vfloat4 __attribute__((ext_vector_type(4)));

__global__ __launch_bounds__(64) void lif_kernel(const float* __restrict__ x,
                                                 const float* __restrict__ decay_p,
                                                 float* __restrict__ out,
                                                 int n_neurons) {
    __shared__ vfloat4 lds4[W * K];   // 25,600 B flat mirror of this block's slab

    const int lane = threadIdx.x;
    const float decay = decay_p[0];
    const size_t base_f4 = (size_t)blockIdx.x * (W * K);

    const vfloat4* __restrict__ g4 = (const vfloat4*)x + base_f4;
    vfloat4* __restrict__ o4 = (vfloat4*)out + base_f4;

    // ---- Stage: 25 coalesced 1 KB wave-wide loads, all issued before any
    // LDS write (25.6 KB outstanding per wave), then ds_write_b128 into the
    // flat slab layout.
    vfloat4 v[K];
    #pragma unroll
    for (int k = 0; k < K; ++k) v[k] = g4[k * W + lane];
    #pragma unroll
    for (int k = 0; k < K; ++k) lds4[k * W + lane] = v[k];

    // ---- Compute: lane owns neuron `lane`; row = float4s [lane*K, lane*K+K).
    // In-place overwrite x -> o. (Single wave: no barrier needed; compiler
    // orders ds ops via lgkmcnt.)
    float u = 0.0f, o = 0.0f;
    #pragma unroll
    for (int i = 0; i < K; ++i) {
        vfloat4 t = lds4[lane * K + i];
        u = decay * u + t.x - o * VTH; o = (u > VTH) ? 1.0f : 0.0f; t.x = o;
        u = decay * u + t.y - o * VTH; o = (u > VTH) ? 1.0f : 0.0f; t.y = o;
        u = decay * u + t.z - o * VTH; o = (u > VTH) ? 1.0f : 0.0f; t.z = o;
        u = decay * u + t.w - o * VTH; o = (u > VTH) ? 1.0f : 0.0f; t.w = o;
        lds4[lane * K + i] = t;
    }

    // ---- Store: lane-contiguous LDS reads (2-way max = free), line-perfect
    // 1 KB wave-wide non-temporal stores.
    #pragma unroll
    for (int k = 0; k < K; ++k) {
        __builtin_nontemporal_store(lds4[k * W + lane], &o4[k * W + lane]);
    }
}

extern "C" void kernel_launch(void* const* d_in, const int* in_sizes, int n_in,
                              void* d_out, int out_size, void* d_ws, size_t ws_size,
                              hipStream_t stream) {
    const float* x = (const float*)d_in[0];
    const float* decay = (const float*)d_in[1];
    float* out = (float*)d_out;

    const int n_neurons = in_sizes[0] / T_STEPS;   // 262,144
    const int grid = n_neurons / W;                // 4096 single-wave blocks

    lif_kernel<<<grid, W, 0, stream>>>(x, decay, out, n_neurons);
}